// Round 3
// baseline (158.218 us; speedup 1.0000x reference)
//
#include <hip/hip_runtime.h>
#include <math.h>

#define BATCH 16
#define OC_TOT 512
#define HH 128
#define WW 128
#define KK 5
#define NOC 32      // output channels per block
#define ROWS 16     // output rows per block
#define NTHREADS 256
#define HW (HH * WW)
#define TAPS 28     // 25 taps + bias + 2 pad, per oc

// ---------------- kernel 1: rotated tap table (512 x 28 floats) ----------------
__global__ void tap_kernel(const float* __restrict__ weight,
                           const float* __restrict__ bias,
                           float* __restrict__ tw)
{
    int idx = blockIdx.x * NTHREADS + threadIdx.x;
    if (idx >= OC_TOT * TAPS) return;
    int oc = idx / TAPS;
    int t  = idx - oc * TAPS;
    int o  = oc >> 4;
    int r  = oc & 15;
    float val = 0.0f;
    if (t == 25) {
        val = bias[o];
    } else if (t < 25) {
        int ky = t / 5;
        int kx = t - ky * 5;
        const float* wp = weight + o * 25;   // d=1 -> z-interp selects plane 0 exactly
        float theta = 0.39269908169872414f * (float)r;   // 2*pi/16 * r
        float cth = cosf(theta), sth = sinf(theta);
        float ty = ((float)ky + 0.5f) * (2.0f / (float)KK) - 1.0f;
        float tx = ((float)kx + 0.5f) * (2.0f / (float)KK) - 1.0f;
        float xi =  cth * tx + sth * ty;
        float yi = -sth * tx + cth * ty;
        float px = (xi + 1.0f) * ((float)KK * 0.5f) - 0.5f;
        float py = (yi + 1.0f) * ((float)KK * 0.5f) - 0.5f;
        float fx0 = floorf(px), fy0 = floorf(py);
        int   x0 = (int)fx0,  y0 = (int)fy0;
        float wx = px - fx0,  wy = py - fy0;
        float v00 = (y0 >= 0   && y0 < KK   && x0 >= 0   && x0 < KK  ) ? wp[y0 * KK + x0]         : 0.0f;
        float v01 = (y0 >= 0   && y0 < KK   && x0+1 >= 0 && x0+1 < KK) ? wp[y0 * KK + x0 + 1]     : 0.0f;
        float v10 = (y0+1 >= 0 && y0+1 < KK && x0 >= 0   && x0 < KK  ) ? wp[(y0+1) * KK + x0]     : 0.0f;
        float v11 = (y0+1 >= 0 && y0+1 < KK && x0+1 >= 0 && x0+1 < KK) ? wp[(y0+1) * KK + x0 + 1] : 0.0f;
        val = v00 * (1.0f - wy) * (1.0f - wx)
            + v01 * (1.0f - wy) * wx
            + v10 * wy * (1.0f - wx)
            + v11 * wy * wx;
    }
    tw[idx] = val;
}

// ---------------- kernel 2: conv; taps come in via the SCALAR pipe ----------------
__global__ __launch_bounds__(NTHREADS, 4)
void groupconv_kernel(const float* __restrict__ x,
                      const float* __restrict__ tw,
                      float* __restrict__ out)
{
    __shared__ float sIn[ROWS + 4][WW + 4];   // 20 x 132 input tile (zero halo)

    const int tid = threadIdx.x;
    const int bid = blockIdx.x;
    // grid = BATCH * (HH/ROWS) * (OC_TOT/NOC) = 16*8*16 = 2048
    const int octile = bid & 15;
    const int htile  = (bid >> 4) & 7;
    const int b      = bid >> 7;
    const int h0     = htile * ROWS;
    const int ocbase = octile * NOC;

    // ---- stage input tile (with zero halo) ----
    const float* xb = x + b * HW;
    for (int idx = tid; idx < (ROWS + 4) * (WW + 4); idx += NTHREADS) {
        int ry = idx / (WW + 4);
        int cx = idx - ry * (WW + 4);
        int gy = h0 - 2 + ry;
        int gx = cx - 2;
        float v = 0.0f;
        if (gy >= 0 && gy < HH && gx >= 0 && gx < WW)
            v = xb[gy * WW + gx];
        sIn[ry][cx] = v;
    }
    __syncthreads();

    // ---- each thread = 1 row x 8 cols, loop 32 ocs ----
    const int row  = tid >> 4;          // 0..15
    const int wcol = (tid & 15) * 8;    // 0,8,...,120
    const int h    = h0 + row;

    // 5x12 input window in registers (15 ds_read_b128, one-time)
    float win[5][12];
#pragma unroll
    for (int r5 = 0; r5 < 5; ++r5) {
        float4 a = *(const float4*)&sIn[row + r5][wcol];
        float4 c = *(const float4*)&sIn[row + r5][wcol + 4];
        float4 e = *(const float4*)&sIn[row + r5][wcol + 8];
        win[r5][0] = a.x; win[r5][1]  = a.y; win[r5][2]  = a.z; win[r5][3]  = a.w;
        win[r5][4] = c.x; win[r5][5]  = c.y; win[r5][6]  = c.z; win[r5][7]  = c.w;
        win[r5][8] = e.x; win[r5][9]  = e.y; win[r5][10] = e.z; win[r5][11] = e.w;
    }

    // block-uniform tap base -> compiler emits s_load (constant cache, SGPRs)
    const float* twp = tw + (size_t)ocbase * TAPS;

    float* op = out + ((size_t)b * OC_TOT + ocbase) * (size_t)HW
                    + (size_t)h * WW + wcol;
    for (int i = 0; i < NOC; ++i) {
        const float* tp = twp + i * TAPS;    // uniform address: scalar loads
        float bz = tp[25];
        float a0 = bz, a1 = bz, a2 = bz, a3 = bz, a4 = bz, a5 = bz, a6 = bz, a7 = bz;
#pragma unroll
        for (int ky = 0; ky < 5; ++ky) {
#pragma unroll
            for (int kx = 0; kx < 5; ++kx) {
                float wv = tp[ky * 5 + kx];  // SGPR operand of v_fmac
                a0 = fmaf(win[ky][kx],     wv, a0);
                a1 = fmaf(win[ky][kx + 1], wv, a1);
                a2 = fmaf(win[ky][kx + 2], wv, a2);
                a3 = fmaf(win[ky][kx + 3], wv, a3);
                a4 = fmaf(win[ky][kx + 4], wv, a4);
                a5 = fmaf(win[ky][kx + 5], wv, a5);
                a6 = fmaf(win[ky][kx + 6], wv, a6);
                a7 = fmaf(win[ky][kx + 7], wv, a7);
            }
        }
        *(float4*)op       = make_float4(a0, a1, a2, a3);
        *(float4*)(op + 4) = make_float4(a4, a5, a6, a7);
        op += HW;
    }
}

extern "C" void kernel_launch(void* const* d_in, const int* in_sizes, int n_in,
                              void* d_out, int out_size, void* d_ws, size_t ws_size,
                              hipStream_t stream)
{
    const float* x      = (const float*)d_in[0];  // (16,1,128,128)
    const float* weight = (const float*)d_in[1];  // (32,1,1,5,5)
    const float* bias   = (const float*)d_in[2];  // (32,)
    float* out = (float*)d_out;                   // (16,32,16,128,128)
    float* tw  = (float*)d_ws;                    // 512*28 floats = 57344 B scratch

    const int ntap = OC_TOT * TAPS;
    tap_kernel<<<(ntap + NTHREADS - 1) / NTHREADS, NTHREADS, 0, stream>>>(weight, bias, tw);

    const int nblocks = BATCH * (HH / ROWS) * (OC_TOT / NOC);  // 2048
    groupconv_kernel<<<nblocks, NTHREADS, 0, stream>>>(x, tw, out);
}